// Round 1
// baseline (181.169 us; speedup 1.0000x reference)
//
#include <hip/hip_runtime.h>
#include <hip/hip_bf16.h>

// SimpleOrdinalLinearDecayEmbedding: out[m,d] = gate[m] * (q[m,:]@Wq[d,:]) + bq[d]
// gate[m] = sigmoid(sum_k max(1-|k-r[m]|/3,0)*Wr[k] + br), r in {0..3} -> 4-entry LUT.
// M = B*S = 32768, K = Q = 800, N = D = 64. Memory-bound (105 MB q stream).

#define QD 800
#define DD 64
#define M_TOTAL 32768

typedef __attribute__((ext_vector_type(8))) short bf16x8;
typedef __attribute__((ext_vector_type(4))) float f32x4;

static __device__ __forceinline__ short f2bf(float f) {
  union { __hip_bfloat16 h; short s; } u;
  u.h = __float2bfloat16(f);
  return u.s;
}

static __device__ __forceinline__ bf16x8 load_cvt8(const float* __restrict__ p) {
  f32x4 lo = *reinterpret_cast<const f32x4*>(p);
  f32x4 hi = *reinterpret_cast<const f32x4*>(p + 4);
  bf16x8 r;
  r[0] = f2bf(lo.x); r[1] = f2bf(lo.y); r[2] = f2bf(lo.z); r[3] = f2bf(lo.w);
  r[4] = f2bf(hi.x); r[5] = f2bf(hi.y); r[6] = f2bf(hi.z); r[7] = f2bf(hi.w);
  return r;
}

// Prep: Wq fp32 [64][800] -> bf16 row-major in workspace (51200 elems).
__global__ void convert_wq_kernel(const float* __restrict__ Wq, short* __restrict__ Bb) {
  int i = (blockIdx.x * 256 + threadIdx.x) * 4;
  f32x4 v = *reinterpret_cast<const f32x4*>(Wq + i);
  short4 o;
  o.x = f2bf(v.x); o.y = f2bf(v.y); o.z = f2bf(v.z); o.w = f2bf(v.w);
  *reinterpret_cast<short4*>(Bb + i) = o;
}

// Main GEMM. One wave per 16-row M-subtile; 4 accumulators cover all 64 cols.
// A fragments: direct fp32 global loads (32 contiguous B/lane, rows 3200B apart
// = 128-aligned full cache lines), converted in-register. B fragments: bf16
// 16B/lane loads from workspace (L1/L2 resident, 204KB total).
template <bool USE_WS>
__global__ __launch_bounds__(256, 2) void sold_kernel(
    const float* __restrict__ q, const int* __restrict__ rdat,
    const short* __restrict__ Bb, const float* __restrict__ Wq,
    const float* __restrict__ bq, const float* __restrict__ Wr,
    const float* __restrict__ br, float* __restrict__ out) {
  const int lane = threadIdx.x & 63;
  const int wave = threadIdx.x >> 6;
  const int l15 = lane & 15;
  const int lhi = lane >> 4;
  const int m0 = blockIdx.x * 64 + wave * 16;

  // A: lane holds A[m=l15][k=lhi*8+j], j=0..7 (k-permutation shared with B, so
  // any common reordering cancels inside the dot product).
  const float* aptr = q + (size_t)(m0 + l15) * QD + lhi * 8;
  const short* bptr = Bb + l15 * QD + lhi * 8;          // B[k][n]=Wq[n][k]; n=l15
  const float* wptr = Wq + l15 * QD + lhi * 8;

  f32x4 acc0 = {0.f, 0.f, 0.f, 0.f};
  f32x4 acc1 = {0.f, 0.f, 0.f, 0.f};
  f32x4 acc2 = {0.f, 0.f, 0.f, 0.f};
  f32x4 acc3 = {0.f, 0.f, 0.f, 0.f};

#pragma unroll 5
  for (int kt = 0; kt < 25; ++kt) {
    const int ko = kt * 32;
    bf16x8 a = load_cvt8(aptr + ko);
    bf16x8 b0, b1, b2, b3;
    if constexpr (USE_WS) {
      b0 = *reinterpret_cast<const bf16x8*>(bptr + ko);
      b1 = *reinterpret_cast<const bf16x8*>(bptr + 16 * QD + ko);
      b2 = *reinterpret_cast<const bf16x8*>(bptr + 32 * QD + ko);
      b3 = *reinterpret_cast<const bf16x8*>(bptr + 48 * QD + ko);
    } else {
      b0 = load_cvt8(wptr + ko);
      b1 = load_cvt8(wptr + 16 * QD + ko);
      b2 = load_cvt8(wptr + 32 * QD + ko);
      b3 = load_cvt8(wptr + 48 * QD + ko);
    }
    acc0 = __builtin_amdgcn_mfma_f32_16x16x32_bf16(a, b0, acc0, 0, 0, 0);
    acc1 = __builtin_amdgcn_mfma_f32_16x16x32_bf16(a, b1, acc1, 0, 0, 0);
    acc2 = __builtin_amdgcn_mfma_f32_16x16x32_bf16(a, b2, acc2, 0, 0, 0);
    acc3 = __builtin_amdgcn_mfma_f32_16x16x32_bf16(a, b3, acc3, 0, 0, 0);
  }

  // Gate LUT: r in {0..3}; weights w[k]=max(1-|k-r|/3,0).
  float wr[4] = {Wr[0], Wr[1], Wr[2], Wr[3]};
  float brv = br[0];
  float lut[4];
  const float inv3 = 1.0f / 3.0f;
#pragma unroll
  for (int r = 0; r < 4; ++r) {
    float s = brv;
#pragma unroll
    for (int k = 0; k < 4; ++k) {
      float w = fmaxf(1.0f - fabsf((float)(k - r)) * inv3, 0.0f);
      s += w * wr[k];
    }
    lut[r] = 1.0f / (1.0f + __expf(-s));
  }

  float bqv0 = bq[0 * 16 + l15];
  float bqv1 = bq[1 * 16 + l15];
  float bqv2 = bq[2 * 16 + l15];
  float bqv3 = bq[3 * 16 + l15];

  // D layout (HW-verified m89): col = lane&15 (+16*dt), row = (lane>>4)*4 + reg.
#pragma unroll
  for (int r = 0; r < 4; ++r) {
    int row = m0 + lhi * 4 + r;
    float g = lut[rdat[row]];
    float* orow = out + (size_t)row * DD + l15;
    orow[0]  = acc0[r] * g + bqv0;
    orow[16] = acc1[r] * g + bqv1;
    orow[32] = acc2[r] * g + bqv2;
    orow[48] = acc3[r] * g + bqv3;
  }
}

extern "C" void kernel_launch(void* const* d_in, const int* in_sizes, int n_in,
                              void* d_out, int out_size, void* d_ws, size_t ws_size,
                              hipStream_t stream) {
  const float* q    = (const float*)d_in[0];  // [64,512,800] f32
  const int*   rdat = (const int*)d_in[1];    // [64,512] i32
  const float* Wq   = (const float*)d_in[2];  // [64,800] f32
  const float* bq   = (const float*)d_in[3];  // [64] f32
  const float* Wr   = (const float*)d_in[4];  // [1,4] f32
  const float* br   = (const float*)d_in[5];  // [1] f32
  float* out = (float*)d_out;                 // [64,512,64] f32

  const size_t need_ws = (size_t)DD * QD * sizeof(short);  // 102400 B
  if (ws_size >= need_ws) {
    short* Bb = (short*)d_ws;
    convert_wq_kernel<<<(DD * QD / 4 + 255) / 256, 256, 0, stream>>>(Wq, Bb);
    sold_kernel<true><<<M_TOTAL / 64, 256, 0, stream>>>(q, rdat, Bb, Wq, bq, Wr, br, out);
  } else {
    sold_kernel<false><<<M_TOTAL / 64, 256, 0, stream>>>(q, rdat, nullptr, Wq, bq, Wr, br, out);
  }
}

// Round 3
// 179.840 us; speedup vs baseline: 1.0074x; 1.0074x over previous
//
#include <hip/hip_runtime.h>
#include <hip/hip_bf16.h>

// SimpleOrdinalLinearDecayEmbedding: out[m,d] = gate[m] * (q[m,:]@Wq[d,:]) + bq[d]
// gate[m] = sigmoid(sum_k max(1-|k-r[m]|/3,0)*Wr[k] + br), r in {0..3} -> 4-entry LUT.
// M = B*S = 32768, K = Q = 800, N = D = 64. Memory-bound (105 MB q stream, floor ~18us).
//
// R3 = R2 minus the compile error. k-slot permutation sigma(lhi,j) =
// (j<4 ? lhi*4+j : 16+lhi*4+j-4) applied identically to A and B fragments so every A
// dwordx4 covers FULL 64B cache lines (4 lanes tile each row's 64B); B pre-swizzled
// into per-(kt,acc,lane) fragment order so each B load is one contiguous 1KB wave
// read. Halves TA line-touches per K-iter vs R1.

#define QD 800
#define DD 64
#define M_TOTAL 32768
#define KT 25  // 800 / 32

typedef __attribute__((ext_vector_type(8))) short bf16x8;
typedef __attribute__((ext_vector_type(4))) float f32x4;

static __device__ __forceinline__ short f2bf(float f) {
  union { __hip_bfloat16 h; short s; } u;
  u.h = __float2bfloat16(f);
  return u.s;
}

// Load 8 floats for MFMA slots (lhi, j=0..7) with the sigma permutation:
// regs 0..3 <- p[0..3] (= row_base + lhi*4), regs 4..7 <- p[16..19] (+16 floats).
// Caller passes p = row_base + lhi*4 (+ kt*32).
static __device__ __forceinline__ bf16x8 load_split8(const float* __restrict__ p) {
  f32x4 lo = *reinterpret_cast<const f32x4*>(p);
  f32x4 hi = *reinterpret_cast<const f32x4*>(p + 16);
  bf16x8 r;
  r[0] = f2bf(lo.x); r[1] = f2bf(lo.y); r[2] = f2bf(lo.z); r[3] = f2bf(lo.w);
  r[4] = f2bf(hi.x); r[5] = f2bf(hi.y); r[6] = f2bf(hi.z); r[7] = f2bf(hi.w);
  return r;
}

// Prep: write B as a swizzled bf16 blob. Chunk idx = (kt*4 + acc)*64 + lane holds the
// 8 bf16 B-fragment values for that (kt, acc, lane): Wq[acc*16+(lane&15)][kt*32+sigma].
// 6400 chunks x 16 B = 100 KB.
__global__ void convert_wq_kernel(const float* __restrict__ Wq, short* __restrict__ Bb) {
  int idx = blockIdx.x * 256 + threadIdx.x;  // 6400 threads
  int kt = idx >> 8;
  int acc = (idx >> 6) & 3;
  int lane = idx & 63;
  int l15 = lane & 15, lhi = lane >> 4;
  const float* p = Wq + (acc * 16 + l15) * QD + kt * 32 + lhi * 4;
  bf16x8 r = load_split8(p);
  *reinterpret_cast<bf16x8*>(Bb + (size_t)idx * 8) = r;
}

// Main GEMM: one wave per 16-row M-subtile, 4 accumulators cover all 64 cols.
template <bool USE_WS>
__global__ __launch_bounds__(256, 2) void sold_kernel(
    const float* __restrict__ q, const int* __restrict__ rdat,
    const short* __restrict__ Bb, const float* __restrict__ Wq,
    const float* __restrict__ bq, const float* __restrict__ Wr,
    const float* __restrict__ br, float* __restrict__ out) {
  const int lane = threadIdx.x & 63;
  const int wave = threadIdx.x >> 6;
  const int l15 = lane & 15;
  const int lhi = lane >> 4;
  const int m0 = blockIdx.x * 64 + wave * 16;

  // A base: row = m0 + l15, sigma offset lhi*4 floats (lo), +16 floats (hi).
  const float* aptr = q + (size_t)(m0 + l15) * QD + lhi * 4;
  // B blob: per-kt stride = 4 accs * 64 lanes * 8 shorts = 2048 shorts; acc stride 512.
  const short* bptr = Bb + (size_t)lane * 8;
  // Fallback (no ws): same sigma layout read directly from fp32 Wq.
  const float* w0 = Wq + (0 * 16 + l15) * QD + lhi * 4;
  const float* w1 = Wq + (1 * 16 + l15) * QD + lhi * 4;
  const float* w2 = Wq + (2 * 16 + l15) * QD + lhi * 4;
  const float* w3 = Wq + (3 * 16 + l15) * QD + lhi * 4;

  f32x4 acc0 = {0.f, 0.f, 0.f, 0.f};
  f32x4 acc1 = {0.f, 0.f, 0.f, 0.f};
  f32x4 acc2 = {0.f, 0.f, 0.f, 0.f};
  f32x4 acc3 = {0.f, 0.f, 0.f, 0.f};

#pragma unroll 5
  for (int kt = 0; kt < KT; ++kt) {
    bf16x8 a = load_split8(aptr + kt * 32);
    bf16x8 b0, b1, b2, b3;
    if constexpr (USE_WS) {
      const short* bp = bptr + kt * 2048;
      b0 = *reinterpret_cast<const bf16x8*>(bp + 0 * 512);
      b1 = *reinterpret_cast<const bf16x8*>(bp + 1 * 512);
      b2 = *reinterpret_cast<const bf16x8*>(bp + 2 * 512);
      b3 = *reinterpret_cast<const bf16x8*>(bp + 3 * 512);
    } else {
      b0 = load_split8(w0 + kt * 32);
      b1 = load_split8(w1 + kt * 32);
      b2 = load_split8(w2 + kt * 32);
      b3 = load_split8(w3 + kt * 32);
    }
    acc0 = __builtin_amdgcn_mfma_f32_16x16x32_bf16(a, b0, acc0, 0, 0, 0);
    acc1 = __builtin_amdgcn_mfma_f32_16x16x32_bf16(a, b1, acc1, 0, 0, 0);
    acc2 = __builtin_amdgcn_mfma_f32_16x16x32_bf16(a, b2, acc2, 0, 0, 0);
    acc3 = __builtin_amdgcn_mfma_f32_16x16x32_bf16(a, b3, acc3, 0, 0, 0);
  }

  // Gate LUT: r in {0..3}; weights w[k] = max(1-|k-r|/3, 0).
  float wr[4] = {Wr[0], Wr[1], Wr[2], Wr[3]};
  float brv = br[0];
  float lut[4];
  const float inv3 = 1.0f / 3.0f;
#pragma unroll
  for (int r = 0; r < 4; ++r) {
    float s = brv;
#pragma unroll
    for (int k = 0; k < 4; ++k) {
      float w = fmaxf(1.0f - fabsf((float)(k - r)) * inv3, 0.0f);
      s += w * wr[k];
    }
    lut[r] = 1.0f / (1.0f + __expf(-s));
  }

  float bqv0 = bq[0 * 16 + l15];
  float bqv1 = bq[1 * 16 + l15];
  float bqv2 = bq[2 * 16 + l15];
  float bqv3 = bq[3 * 16 + l15];

  // D layout (HW-verified m89): col = lane&15 (+16 per acc), row = (lane>>4)*4 + reg.
#pragma unroll
  for (int r = 0; r < 4; ++r) {
    int row = m0 + lhi * 4 + r;
    float g = lut[rdat[row]];
    float* orow = out + (size_t)row * DD + l15;
    orow[0]  = acc0[r] * g + bqv0;
    orow[16] = acc1[r] * g + bqv1;
    orow[32] = acc2[r] * g + bqv2;
    orow[48] = acc3[r] * g + bqv3;
  }
}

extern "C" void kernel_launch(void* const* d_in, const int* in_sizes, int n_in,
                              void* d_out, int out_size, void* d_ws, size_t ws_size,
                              hipStream_t stream) {
  const float* q    = (const float*)d_in[0];  // [64,512,800] f32
  const int*   rdat = (const int*)d_in[1];    // [64,512] i32
  const float* Wq   = (const float*)d_in[2];  // [64,800] f32
  const float* bq   = (const float*)d_in[3];  // [64] f32
  const float* Wr   = (const float*)d_in[4];  // [1,4] f32
  const float* br   = (const float*)d_in[5];  // [1] f32
  float* out = (float*)d_out;                 // [64,512,64] f32

  const size_t need_ws = (size_t)KT * 4 * 64 * 8 * sizeof(short);  // 102400 B
  if (ws_size >= need_ws) {
    short* Bb = (short*)d_ws;
    convert_wq_kernel<<<KT, 256, 0, stream>>>(Wq, Bb);  // 25*256 = 6400 threads
    sold_kernel<true><<<M_TOTAL / 64, 256, 0, stream>>>(q, rdat, Bb, Wq, bq, Wr, br, out);
  } else {
    sold_kernel<false><<<M_TOTAL / 64, 256, 0, stream>>>(q, rdat, nullptr, Wq, bq, Wr, br, out);
  }
}